// Round 3
// baseline (202.727 us; speedup 1.0000x reference)
//
#include <hip/hip_runtime.h>
#include <hip/hip_cooperative_groups.h>
#include <math.h>

namespace cg = cooperative_groups;

#define H 2048
#define L 350
#define NB 512           // 2 blocks/CU x 256 CUs — half the co-residency limit
#define G1 3072          // gh rows done in phase A (rest in phase B)

__device__ __forceinline__ float dot4(float4 a, float4 b, float acc) {
    acc = fmaf(a.x, b.x, acc);
    acc = fmaf(a.y, b.y, acc);
    acc = fmaf(a.z, b.z, acc);
    acc = fmaf(a.w, b.w, acc);
    return acc;
}

__device__ __forceinline__ float wsum(float v) {
    #pragma unroll
    for (int m = 1; m < 64; m <<= 1) v += __shfl_xor(v, m, 64);
    return v;   // all lanes hold the sum
}
__device__ __forceinline__ float wmax(float v) {
    #pragma unroll
    for (int m = 1; m < 64; m <<= 1) v = fmaxf(v, __shfl_xor(v, m, 64));
    return v;
}

// ---- Phase A: attn logits (350 rows, 16KB each) + gh rows [0, G1) (8KB each)
__device__ void phaseA(int b, int nb,
    const float4* x4, const float4* h4,
    const float* attn_W, const float* attn_b,
    const float* w_hh, const float* b_hh,
    float* logits, float* gh)
{
    const int w = threadIdx.x >> 6, lane = threadIdx.x & 63;
    const int nwaves = nb * 4;
    for (int item = b * 4 + w; item < L + G1; item += nwaves) {
        if (item < L) {
            const float4* Wr = reinterpret_cast<const float4*>(attn_W + (size_t)item * (2 * H));
            float acc = 0.f;
            #pragma unroll
            for (int i = lane; i < H / 4; i += 64) {
                acc = dot4(Wr[i], x4[i], acc);
                acc = dot4(Wr[H / 4 + i], h4[i], acc);
            }
            acc = wsum(acc);
            if (lane == 0) logits[item] = acc + attn_b[item];
        } else {
            const int row = item - L;
            const float4* Wr = reinterpret_cast<const float4*>(w_hh + (size_t)row * H);
            float acc = 0.f;
            #pragma unroll
            for (int i = lane; i < H / 4; i += 64) acc = dot4(Wr[i], h4[i], acc);
            acc = wsum(acc);
            if (lane == 0) gh[row] = acc + b_hh[row];
        }
    }
}

// ---- Phase B: blocks 0..7 do softmax (redundant, deterministic) + context
//      slice; blocks 8.. do gh rows [G1, 3H)
__device__ void phaseB(int b, int nb,
    const float4* h4, const float* enc,
    const float* w_hh, const float* b_hh,
    const float* logits, float* gh, float* ctx, float* attn_out)
{
    const int tid = threadIdx.x, w = tid >> 6, lane = tid & 63;
    if (b < 8) {
        __shared__ float attn_s[L];
        __shared__ float smax[4], ssum[4];
        float v0 = logits[tid];
        float v1 = (tid + 256 < L) ? logits[tid + 256] : -INFINITY;
        float m = wmax(fmaxf(v0, v1));
        if (lane == 0) smax[w] = m;
        __syncthreads();
        m = fmaxf(fmaxf(smax[0], smax[1]), fmaxf(smax[2], smax[3]));
        float e0 = expf(v0 - m);
        float e1 = (tid + 256 < L) ? expf(v1 - m) : 0.f;
        float s = wsum(e0 + e1);
        if (lane == 0) ssum[w] = s;
        __syncthreads();
        const float inv = 1.f / (ssum[0] + ssum[1] + ssum[2] + ssum[3]);
        attn_s[tid] = e0 * inv;
        if (tid + 256 < L) attn_s[tid + 256] = e1 * inv;
        if (b == 0) {
            attn_out[tid] = e0 * inv;
            if (tid + 256 < L) attn_out[tid + 256] = e1 * inv;
        }
        __syncthreads();
        const int i = b * 256 + tid;
        const float* ec = enc + i;
        float acc0 = 0.f, acc1 = 0.f;
        for (int j = 0; j < L; j += 2) {
            acc0 = fmaf(attn_s[j],     ec[(size_t)j * H],       acc0);
            acc1 = fmaf(attn_s[j + 1], ec[(size_t)(j + 1) * H], acc1);
        }
        ctx[i] = acc0 + acc1;
    } else {
        const int nwaves = (nb - 8) * 4;
        for (int gwp = (b - 8) * 4 + w; gwp < 3 * H - G1; gwp += nwaves) {
            const int row = G1 + gwp;
            const float4* Wr = reinterpret_cast<const float4*>(w_hh + (size_t)row * H);
            float acc = 0.f;
            #pragma unroll
            for (int i = lane; i < H / 4; i += 64) acc = dot4(Wr[i], h4[i], acc);
            acc = wsum(acc);
            if (lane == 0) gh[row] = acc + b_hh[row];
        }
    }
}

// ---- Phase C: g = relu([x, ctx] @ comb_W.T + b), one wave per row
__device__ void phaseC(int b, int nb,
    const float4* x4, const float4* c4,
    const float* comb_W, const float* comb_b, float* g)
{
    const int w = threadIdx.x >> 6, lane = threadIdx.x & 63;
    const int nwaves = nb * 4;
    for (int r = b * 4 + w; r < H; r += nwaves) {
        const float4* Wr = reinterpret_cast<const float4*>(comb_W + (size_t)r * (2 * H));
        float acc = 0.f;
        #pragma unroll
        for (int i = lane; i < H / 4; i += 64) {
            acc = dot4(Wr[i], x4[i], acc);
            acc = dot4(Wr[H / 4 + i], c4[i], acc);
        }
        acc = wsum(acc);
        if (lane == 0) g[r] = fmaxf(acc + comb_b[r], 0.f);
    }
}

// ---- Phase D: gi GEMV (3 rows per item) + GRU gates, one wave per item
__device__ void phaseD(int b, int nb,
    const float4* g4, const float* hidden,
    const float* w_ih, const float* b_ih,
    const float* gh, float* out)
{
    const int w = threadIdx.x >> 6, lane = threadIdx.x & 63;
    const int nwaves = nb * 4;
    for (int item = b * 4 + w; item < H; item += nwaves) {
        const float4* Wr0 = reinterpret_cast<const float4*>(w_ih + (size_t)item * H);
        const float4* Wr1 = reinterpret_cast<const float4*>(w_ih + (size_t)(item + H) * H);
        const float4* Wr2 = reinterpret_cast<const float4*>(w_ih + (size_t)(item + 2 * H) * H);
        float ar = 0.f, az = 0.f, an = 0.f;
        #pragma unroll
        for (int i = lane; i < H / 4; i += 64) {
            const float4 gv = g4[i];
            ar = dot4(Wr0[i], gv, ar);
            az = dot4(Wr1[i], gv, az);
            an = dot4(Wr2[i], gv, an);
        }
        ar = wsum(ar); az = wsum(az); an = wsum(an);
        if (lane == 0) {
            const float ir  = ar + b_ih[item];
            const float iz  = az + b_ih[item + H];
            const float in_ = an + b_ih[item + 2 * H];
            const float r = 1.f / (1.f + expf(-(ir + gh[item])));
            const float z = 1.f / (1.f + expf(-(iz + gh[item + H])));
            const float n = tanhf(in_ + r * gh[item + 2 * H]);
            const float hnew = (1.f - z) * n + z * hidden[item];
            out[item] = hnew;
            out[H + item] = hnew;
        }
    }
}

// =================== fused cooperative kernel ===================
__global__ __launch_bounds__(256, 2) void fused_decoder_kernel(
    const float* __restrict__ input, const float* __restrict__ hidden,
    const float* __restrict__ enc,
    const float* __restrict__ attn_W, const float* __restrict__ attn_b,
    const float* __restrict__ comb_W, const float* __restrict__ comb_b,
    const float* __restrict__ w_ih, const float* __restrict__ w_hh,
    const float* __restrict__ b_ih, const float* __restrict__ b_hh,
    float* __restrict__ out, float* __restrict__ ws)
{
    cg::grid_group grid = cg::this_grid();
    float* logits = ws;            // 350
    float* gh     = ws + 512;      // 6144
    float* g      = ws + 7168;     // 2048
    float* ctx    = ws + 9216;     // 2048
    const int b = blockIdx.x, nb = gridDim.x;
    const float4* x4 = reinterpret_cast<const float4*>(input);
    const float4* h4 = reinterpret_cast<const float4*>(hidden);

    phaseA(b, nb, x4, h4, attn_W, attn_b, w_hh, b_hh, logits, gh);
    grid.sync();
    phaseB(b, nb, h4, enc, w_hh, b_hh, logits, gh, ctx, out + 2 * H);
    grid.sync();
    phaseC(b, nb, x4, reinterpret_cast<const float4*>(ctx), comb_W, comb_b, g);
    grid.sync();
    phaseD(b, nb, reinterpret_cast<const float4*>(g), hidden, w_ih, b_ih, gh, out);
}

// =================== fallback: per-phase kernels ===================
__global__ __launch_bounds__(256) void kA(
    const float* input, const float* hidden,
    const float* attn_W, const float* attn_b,
    const float* w_hh, const float* b_hh, float* logits, float* gh)
{
    phaseA(blockIdx.x, gridDim.x,
           reinterpret_cast<const float4*>(input), reinterpret_cast<const float4*>(hidden),
           attn_W, attn_b, w_hh, b_hh, logits, gh);
}
__global__ __launch_bounds__(256) void kB(
    const float* hidden, const float* enc,
    const float* w_hh, const float* b_hh,
    const float* logits, float* gh, float* ctx, float* attn_out)
{
    phaseB(blockIdx.x, gridDim.x, reinterpret_cast<const float4*>(hidden),
           enc, w_hh, b_hh, logits, gh, ctx, attn_out);
}
__global__ __launch_bounds__(256) void kC(
    const float* input, const float* ctx,
    const float* comb_W, const float* comb_b, float* g)
{
    phaseC(blockIdx.x, gridDim.x,
           reinterpret_cast<const float4*>(input), reinterpret_cast<const float4*>(ctx),
           comb_W, comb_b, g);
}
__global__ __launch_bounds__(256) void kD(
    const float* g, const float* hidden,
    const float* w_ih, const float* b_ih, const float* gh, float* out)
{
    phaseD(blockIdx.x, gridDim.x,
           reinterpret_cast<const float4*>(g), hidden, w_ih, b_ih, gh, out);
}

extern "C" void kernel_launch(void* const* d_in, const int* in_sizes, int n_in,
                              void* d_out, int out_size, void* d_ws, size_t ws_size,
                              hipStream_t stream)
{
    const float* input  = (const float*)d_in[0];
    const float* hidden = (const float*)d_in[1];
    const float* enc    = (const float*)d_in[2];
    const float* attn_W = (const float*)d_in[3];
    const float* attn_b = (const float*)d_in[4];
    const float* comb_W = (const float*)d_in[5];
    const float* comb_b = (const float*)d_in[6];
    const float* w_ih   = (const float*)d_in[7];
    const float* w_hh   = (const float*)d_in[8];
    const float* b_ih   = (const float*)d_in[9];
    const float* b_hh   = (const float*)d_in[10];
    float* out = (float*)d_out;
    float* ws  = (float*)d_ws;

    float* logits = ws;
    float* gh     = ws + 512;
    float* g      = ws + 7168;
    float* ctx    = ws + 9216;

    void* args[] = {
        (void*)&input, (void*)&hidden, (void*)&enc,
        (void*)&attn_W, (void*)&attn_b, (void*)&comb_W, (void*)&comb_b,
        (void*)&w_ih, (void*)&w_hh, (void*)&b_ih, (void*)&b_hh,
        (void*)&out, (void*)&ws
    };
    hipError_t err = hipLaunchCooperativeKernel((void*)fused_decoder_kernel,
                                                dim3(NB), dim3(256), args, 0, stream);
    if (err != hipSuccess) {
        // fallback: 4 regular launches, same phase functions
        kA<<<856, 256, 0, stream>>>(input, hidden, attn_W, attn_b, w_hh, b_hh, logits, gh);
        kB<<<776, 256, 0, stream>>>(hidden, enc, w_hh, b_hh, logits, gh, ctx, out + 2 * H);
        kC<<<512, 256, 0, stream>>>(input, ctx, comb_W, comb_b, g);
        kD<<<512, 256, 0, stream>>>(g, hidden, w_ih, b_ih, gh, out);
    }
}